// Round 1
// baseline (733.027 us; speedup 1.0000x reference)
//
#include <hip/hip_runtime.h>
#include <math.h>

#define B_ 64
#define T_ 576
#define C_ 768
#define SD_ 512
#define N_ 8192
#define TOK_ (B_*T_)
#define CHUNKS_ 9            // 576 / 64

// ---- workspace layout (float offsets) ----
#define OFF_H       0               // 36864*512 = 18874368
#define OFF_S1      18874368        // 36864 float2 = 73728 f
#define OFF_S2      18948096        // 73728 f
#define OFF_LIST    19021824        // 36864 int
#define OFF_COUNT   19058688        // 64 int
#define OFF_PARTIAL 19058752        // 576*512 = 294912 f
#define OFF_QSUM    19353664        // 32768 f
#define OFF_POOLED  19386432        // 524288 f
#define OFF_P2      19910720        // 524288 f
// total 20435008 floats = ~82 MB

__device__ __forceinline__ float gelu_exact(float x) {
    return 0.5f * x * (1.0f + erff(x * 0.7071067811865475f));
}

__device__ __forceinline__ void mm16(const float (&As)[16][68], const float (&Bs)[16][68],
                                     float (&acc)[4][4], int ty, int tx) {
#pragma unroll
    for (int kk = 0; kk < 16; kk++) {
        const float4 a4 = *(const float4*)&As[kk][ty * 4];
        const float4 b4 = *(const float4*)&Bs[kk][tx * 4];
        const float aa[4] = {a4.x, a4.y, a4.z, a4.w};
        const float bb[4] = {b4.x, b4.y, b4.z, b4.w};
#pragma unroll
        for (int i = 0; i < 4; i++)
#pragma unroll
            for (int j = 0; j < 4; j++)
                acc[i][j] = fmaf(aa[i], bb[j], acc[i][j]);
    }
}

// ---------------- zero scratch ----------------
__global__ void zero_kernel(float* partial, int* count) {
    int i = blockIdx.x * 256 + threadIdx.x;
    if (i < B_ * CHUNKS_ * SD_) partial[i] = 0.0f;
    int j = i - B_ * CHUNKS_ * SD_;
    if (j >= 0 && j < B_) count[j] = 0;
}

// ---------------- compact unmasked tokens per batch ----------------
__global__ void compact_kernel(const int* mask, int* list, int* count) {
    int g = blockIdx.x * 256 + threadIdx.x;
    if (g >= TOK_) return;
    int b = g / T_, t = g % T_;
    if (mask[g] == 0) {
        int slot = atomicAdd(&count[b], 1);
        list[b * T_ + slot] = t;
    }
}

// ---------------- LN1 stats (per compacted token) ----------------
__global__ void ln1_stats_kernel(const float* ft, const int* list, const int* count, float2* stats1) {
    int wave = threadIdx.x >> 6, lane = threadIdx.x & 63;
    int s = blockIdx.x * 4 + wave;          // global slot id 0..36863
    int b = s / T_, slot = s % T_;
    if (slot >= count[b]) return;
    int t = list[b * T_ + slot];
    const float4* row = (const float4*)(ft + (size_t)(b * T_ + t) * C_);
    float sum = 0.f, sq = 0.f;
#pragma unroll
    for (int p = 0; p < 3; p++) {
        float4 v = row[lane + 64 * p];
        sum += (v.x + v.y) + (v.z + v.w);
        sq  += v.x * v.x + v.y * v.y + v.z * v.z + v.w * v.w;
    }
#pragma unroll
    for (int o = 32; o > 0; o >>= 1) { sum += __shfl_xor(sum, o); sq += __shfl_xor(sq, o); }
    if (lane == 0) {
        float mu  = sum * (1.0f / C_);
        float var = fmaxf(sq * (1.0f / C_) - mu * mu, 0.0f);
        stats1[s] = make_float2(mu, 1.0f / sqrtf(var + 1e-5f));
    }
}

// ---------------- GEMM1: h = GELU(LN1(ft_compact) @ w1 + b1) ----------------
__global__ __launch_bounds__(256) void gemm1_kernel(
    const float* __restrict__ ft, const float* __restrict__ w1, const float* __restrict__ b1,
    const float* __restrict__ g1, const float* __restrict__ bl1,
    const int* __restrict__ list, const int* __restrict__ count,
    const float2* __restrict__ stats1, float* __restrict__ h)
{
    int mb = blockIdx.x;                    // b*9 + chunk
    int nb = blockIdx.y;
    int b = mb / CHUNKS_, chunk = mb % CHUNKS_;
    int cnt = count[b];
    int row0 = chunk * 64;
    if (row0 >= cnt) return;

    __shared__ float As[16][68], Bs[16][68];
    __shared__ int   rt[64];
    __shared__ float rmu[64], rrs[64];

    int tid = threadIdx.x;
    if (tid < 64) {
        int slot = row0 + tid;
        bool v = slot < cnt;
        rt[tid] = v ? list[b * T_ + slot] : 0;
        float2 st = v ? stats1[b * T_ + slot] : make_float2(0.f, 0.f);
        rmu[tid] = st.x; rrs[tid] = st.y;
    }
    __syncthreads();

    int lm = tid >> 2, lks = tid & 3;       // A load: row, k-seg
    int lk = tid >> 4, lns = tid & 15;      // B load: k-row, n-seg
    int ty = tid >> 4, tx = tid & 15;
    const float* arow = ft + (size_t)(b * T_ + rt[lm]) * C_;
    float mu = rmu[lm], rs = rrs[lm];
    int n0 = nb * 64;
    float acc[4][4] = {};

    for (int k0 = 0; k0 < C_; k0 += 16) {
        float4 av = *(const float4*)(arow + k0 + lks * 4);
        float4 g4 = *(const float4*)(g1  + k0 + lks * 4);
        float4 l4 = *(const float4*)(bl1 + k0 + lks * 4);
        As[lks * 4 + 0][lm] = fmaf((av.x - mu) * rs, g4.x, l4.x);
        As[lks * 4 + 1][lm] = fmaf((av.y - mu) * rs, g4.y, l4.y);
        As[lks * 4 + 2][lm] = fmaf((av.z - mu) * rs, g4.z, l4.z);
        As[lks * 4 + 3][lm] = fmaf((av.w - mu) * rs, g4.w, l4.w);
        float4 bv = *(const float4*)(w1 + (size_t)(k0 + lk) * SD_ + n0 + lns * 4);
        *(float4*)&Bs[lk][lns * 4] = bv;
        __syncthreads();
        mm16(As, Bs, acc, ty, tx);
        __syncthreads();
    }

    int cnt_here = min(64, cnt - row0);
    float4 bb = *(const float4*)(b1 + n0 + tx * 4);
#pragma unroll
    for (int i = 0; i < 4; i++) {
        int m = ty * 4 + i;
        if (m < cnt_here) {
            float4 o;
            o.x = gelu_exact(acc[i][0] + bb.x);
            o.y = gelu_exact(acc[i][1] + bb.y);
            o.z = gelu_exact(acc[i][2] + bb.z);
            o.w = gelu_exact(acc[i][3] + bb.w);
            *(float4*)(h + (size_t)(b * T_ + row0 + m) * SD_ + n0 + tx * 4) = o;
        }
    }
}

// ---------------- LN2 stats over h ----------------
__global__ void ln2_stats_kernel(const float* h, const int* count, float2* stats2) {
    int wave = threadIdx.x >> 6, lane = threadIdx.x & 63;
    int s = blockIdx.x * 4 + wave;
    int b = s / T_, slot = s % T_;
    if (slot >= count[b]) return;
    const float4* row = (const float4*)(h + (size_t)s * SD_);
    float sum = 0.f, sq = 0.f;
#pragma unroll
    for (int p = 0; p < 2; p++) {
        float4 v = row[lane + 64 * p];
        sum += (v.x + v.y) + (v.z + v.w);
        sq  += v.x * v.x + v.y * v.y + v.z * v.z + v.w * v.w;
    }
#pragma unroll
    for (int o = 32; o > 0; o >>= 1) { sum += __shfl_xor(sum, o); sq += __shfl_xor(sq, o); }
    if (lane == 0) {
        float mu  = sum * (1.0f / SD_);
        float var = fmaxf(sq * (1.0f / SD_) - mu * mu, 0.0f);
        stats2[s] = make_float2(mu, 1.0f / sqrtf(var + 1e-5f));
    }
}

// ---------------- GEMM2: masked col-sums of (LN2(h) @ w2 + b2) ----------------
__global__ __launch_bounds__(256) void gemm2_kernel(
    const float* __restrict__ h, const float* __restrict__ w2, const float* __restrict__ b2,
    const float* __restrict__ g2, const float* __restrict__ bl2,
    const int* __restrict__ count, const float2* __restrict__ stats2, float* __restrict__ partial)
{
    int mb = blockIdx.x, nb = blockIdx.y;
    int b = mb / CHUNKS_, chunk = mb % CHUNKS_;
    int cnt = count[b];
    int row0 = chunk * 64;
    if (row0 >= cnt) return;

    __shared__ float As[16][68], Bs[16][68];
    __shared__ float red[16][68];
    __shared__ float rmu[64], rrs[64], rvf[64];

    int tid = threadIdx.x;
    if (tid < 64) {
        int slot = row0 + tid;
        bool v = slot < cnt;
        float2 st = v ? stats2[b * T_ + slot] : make_float2(0.f, 0.f);
        rmu[tid] = st.x; rrs[tid] = st.y; rvf[tid] = v ? 1.0f : 0.0f;
    }
    __syncthreads();

    int lm = tid >> 2, lks = tid & 3;
    int lk = tid >> 4, lns = tid & 15;
    int ty = tid >> 4, tx = tid & 15;
    const float* arow = h + (size_t)(b * T_ + row0 + lm) * SD_;
    float mu = rmu[lm], rs = rrs[lm], vf = rvf[lm];
    int n0 = nb * 64;
    float acc[4][4] = {};

    for (int k0 = 0; k0 < SD_; k0 += 16) {
        float4 av = *(const float4*)(arow + k0 + lks * 4);
        float4 g4 = *(const float4*)(g2  + k0 + lks * 4);
        float4 l4 = *(const float4*)(bl2 + k0 + lks * 4);
        As[lks * 4 + 0][lm] = fmaf((av.x - mu) * rs, g4.x, l4.x) * vf;
        As[lks * 4 + 1][lm] = fmaf((av.y - mu) * rs, g4.y, l4.y) * vf;
        As[lks * 4 + 2][lm] = fmaf((av.z - mu) * rs, g4.z, l4.z) * vf;
        As[lks * 4 + 3][lm] = fmaf((av.w - mu) * rs, g4.w, l4.w) * vf;
        float4 bv = *(const float4*)(w2 + (size_t)(k0 + lk) * SD_ + n0 + lns * 4);
        *(float4*)&Bs[lk][lns * 4] = bv;
        __syncthreads();
        mm16(As, Bs, acc, ty, tx);
        __syncthreads();
    }

    // per-block column sums (padded rows contributed 0 because A was zeroed)
#pragma unroll
    for (int j = 0; j < 4; j++)
        red[ty][tx * 4 + j] = ((acc[0][j] + acc[1][j]) + (acc[2][j] + acc[3][j]));
    __syncthreads();
    if (tid < 64) {
        float s = 0.f;
#pragma unroll
        for (int yy = 0; yy < 16; yy++) s += red[yy][tid];
        int cnt_here = min(64, cnt - row0);
        partial[(size_t)mb * SD_ + n0 + tid] = fmaf((float)cnt_here, b2[n0 + tid], s);
    }
}

// ---------------- qsum = sum over chunks, scaled by 1/sqrt(512) ----------------
__global__ void qsum_reduce_kernel(const float* partial, float* qsum) {
    int i = blockIdx.x * 256 + threadIdx.x;    // < 32768
    int b = i >> 9, d = i & 511;
    float s = 0.f;
#pragma unroll
    for (int c = 0; c < CHUNKS_; c++) s += partial[((size_t)(b * CHUNKS_ + c)) * SD_ + d];
    qsum[i] = s * 0.04419417382415922f;        // 1/sqrt(512)
}

// ---------------- pooled = qsum @ sd^T ----------------
__global__ __launch_bounds__(256) void pooled_kernel(const float* __restrict__ qsum,
                                                     const float* __restrict__ sd,
                                                     float* __restrict__ pooled) {
    int n0 = blockIdx.x * 64;
    __shared__ float As[16][68], Bs[16][68];
    int tid = threadIdx.x, lm = tid >> 2, lks = tid & 3, ty = tid >> 4, tx = tid & 15;
    float acc[4][4] = {};
    for (int k0 = 0; k0 < SD_; k0 += 16) {
        float4 av = *(const float4*)(qsum + (size_t)lm * SD_ + k0 + lks * 4);
        As[lks * 4 + 0][lm] = av.x; As[lks * 4 + 1][lm] = av.y;
        As[lks * 4 + 2][lm] = av.z; As[lks * 4 + 3][lm] = av.w;
        float4 bv = *(const float4*)(sd + (size_t)(n0 + lm) * SD_ + k0 + lks * 4);
        Bs[lks * 4 + 0][lm] = bv.x; Bs[lks * 4 + 1][lm] = bv.y;
        Bs[lks * 4 + 2][lm] = bv.z; Bs[lks * 4 + 3][lm] = bv.w;
        __syncthreads();
        mm16(As, Bs, acc, ty, tx);
        __syncthreads();
    }
#pragma unroll
    for (int i = 0; i < 4; i++) {
        int bb = ty * 4 + i;
        float4 o = make_float4(acc[i][0], acc[i][1], acc[i][2], acc[i][3]);
        *(float4*)(pooled + (size_t)bb * N_ + n0 + tx * 4) = o;
    }
}

// ---------------- softmax per batch row ----------------
__global__ __launch_bounds__(256) void softmax_kernel(const float* pooled, float* attw) {
    __shared__ float row[N_];
    __shared__ float red[8];
    int b = blockIdx.x, tid = threadIdx.x;
    const float4* src = (const float4*)(pooled + (size_t)b * N_);
    float mx = -3.4e38f;
#pragma unroll
    for (int p = 0; p < 8; p++) {
        float4 v = src[tid + 256 * p];
        *((float4*)&row[(tid + 256 * p) * 4]) = v;
        mx = fmaxf(fmaxf(fmaxf(v.x, v.y), fmaxf(v.z, v.w)), mx);
    }
#pragma unroll
    for (int o = 32; o > 0; o >>= 1) mx = fmaxf(mx, __shfl_xor(mx, o));
    if ((tid & 63) == 0) red[tid >> 6] = mx;
    __syncthreads();
    mx = fmaxf(fmaxf(red[0], red[1]), fmaxf(red[2], red[3]));
    __syncthreads();
    float s = 0.f;
    for (int p = 0; p < 8; p++) {
        int i4 = tid + 256 * p;
        float4 v = *((float4*)&row[i4 * 4]);
        v.x = expf(v.x - mx); v.y = expf(v.y - mx);
        v.z = expf(v.z - mx); v.w = expf(v.w - mx);
        *((float4*)&row[i4 * 4]) = v;
        s += (v.x + v.y) + (v.z + v.w);
    }
#pragma unroll
    for (int o = 32; o > 0; o >>= 1) s += __shfl_xor(s, o);
    if ((tid & 63) == 0) red[tid >> 6] = s;
    __syncthreads();
    s = ((red[0] + red[1]) + (red[2] + red[3]));
    float inv = 1.0f / s;
    float4* dst = (float4*)(attw + (size_t)b * N_);
    for (int p = 0; p < 8; p++) {
        int i4 = tid + 256 * p;
        float4 v = *((float4*)&row[i4 * 4]);
        v.x *= inv; v.y *= inv; v.z *= inv; v.w *= inv;
        dst[i4] = v;
    }
}

// ---------------- att_ft split-K partial GEMM ----------------
__global__ __launch_bounds__(256) void attft_kernel(const float* __restrict__ attw,
                                                    const float* __restrict__ sd,
                                                    float* __restrict__ p2) {
    int n0 = blockIdx.x * 64;
    int kbase = blockIdx.y * 512;
    __shared__ float As[16][68], Bs[16][68];
    int tid = threadIdx.x;
    int lm = tid >> 2, lks = tid & 3, lk = tid >> 4, lns = tid & 15;
    int ty = tid >> 4, tx = tid & 15;
    float acc[4][4] = {};
    for (int k0 = 0; k0 < 512; k0 += 16) {
        float4 av = *(const float4*)(attw + (size_t)lm * N_ + kbase + k0 + lks * 4);
        As[lks * 4 + 0][lm] = av.x; As[lks * 4 + 1][lm] = av.y;
        As[lks * 4 + 2][lm] = av.z; As[lks * 4 + 3][lm] = av.w;
        float4 bv = *(const float4*)(sd + (size_t)(kbase + k0 + lk) * SD_ + n0 + lns * 4);
        *(float4*)&Bs[lk][lns * 4] = bv;
        __syncthreads();
        mm16(As, Bs, acc, ty, tx);
        __syncthreads();
    }
#pragma unroll
    for (int i = 0; i < 4; i++) {
        float4 o = make_float4(acc[i][0], acc[i][1], acc[i][2], acc[i][3]);
        *(float4*)(p2 + ((size_t)(blockIdx.y * 64 + ty * 4 + i)) * SD_ + n0 + tx * 4) = o;
    }
}

__global__ void attft_reduce_kernel(const float* p2, float* att_ft) {
    int i = blockIdx.x * 256 + threadIdx.x;    // < 32768
    int b = i >> 9, d = i & 511;
    float s = 0.f;
#pragma unroll
    for (int kb = 0; kb < 16; kb++) s += p2[((size_t)(kb * 64 + b)) * SD_ + d];
    att_ft[i] = s;
}

__global__ void sdcopy_kernel(const float4* sd, float4* dst) {
    int i = blockIdx.x * 256 + threadIdx.x;    // exactly 1048576 float4
    dst[i] = sd[i];
}

extern "C" void kernel_launch(void* const* d_in, const int* in_sizes, int n_in,
                              void* d_out, int out_size, void* d_ws, size_t ws_size,
                              hipStream_t stream) {
    (void)in_sizes; (void)n_in; (void)out_size; (void)ws_size;
    const float* ft  = (const float*)d_in[0];
    const float* sd  = (const float*)d_in[1];
    const int*   mask= (const int*)d_in[2];
    const float* g1  = (const float*)d_in[3];
    const float* bl1 = (const float*)d_in[4];
    const float* w1  = (const float*)d_in[5];
    const float* b1  = (const float*)d_in[6];
    const float* g2  = (const float*)d_in[7];
    const float* bl2 = (const float*)d_in[8];
    const float* w2  = (const float*)d_in[9];
    const float* b2  = (const float*)d_in[10];
    float* out = (float*)d_out;
    float* ws  = (float*)d_ws;

    float*  h       = ws + OFF_H;
    float2* s1      = (float2*)(ws + OFF_S1);
    float2* s2      = (float2*)(ws + OFF_S2);
    int*    list    = (int*)(ws + OFF_LIST);
    int*    count   = (int*)(ws + OFF_COUNT);
    float*  partial = ws + OFF_PARTIAL;
    float*  qsum    = ws + OFF_QSUM;
    float*  pooled  = ws + OFF_POOLED;
    float*  p2      = ws + OFF_P2;

    float* att_w  = out;
    float* att_ft = out + (size_t)B_ * N_;
    float* sd_out = out + (size_t)B_ * N_ + (size_t)B_ * SD_;

    zero_kernel<<<1153, 256, 0, stream>>>(partial, count);
    compact_kernel<<<144, 256, 0, stream>>>(mask, list, count);
    ln1_stats_kernel<<<TOK_ / 4, 256, 0, stream>>>(ft, list, count, s1);
    gemm1_kernel<<<dim3(B_ * CHUNKS_, SD_ / 64), 256, 0, stream>>>(ft, w1, b1, g1, bl1, list, count, s1, h);
    ln2_stats_kernel<<<TOK_ / 4, 256, 0, stream>>>(h, count, s2);
    gemm2_kernel<<<dim3(B_ * CHUNKS_, SD_ / 64), 256, 0, stream>>>(h, w2, b2, g2, bl2, count, s2, partial);
    qsum_reduce_kernel<<<128, 256, 0, stream>>>(partial, qsum);
    pooled_kernel<<<N_ / 64, 256, 0, stream>>>(qsum, sd, pooled);
    softmax_kernel<<<B_, 256, 0, stream>>>(pooled, att_w);
    attft_kernel<<<dim3(SD_ / 64, 16), 256, 0, stream>>>(att_w, sd, p2);
    attft_reduce_kernel<<<128, 256, 0, stream>>>(p2, att_ft);
    sdcopy_kernel<<<4096, 256, 0, stream>>>((const float4*)sd, (float4*)sd_out);
}

// Round 4
// 474.563 us; speedup vs baseline: 1.5446x; 1.5446x over previous
//
#include <hip/hip_runtime.h>
#include <math.h>

typedef unsigned short u16;
typedef _Float16 half4 __attribute__((ext_vector_type(4)));
typedef _Float16 half8 __attribute__((ext_vector_type(8)));
typedef float f32x4 __attribute__((ext_vector_type(4)));
typedef u16 u16x8 __attribute__((ext_vector_type(8)));

#define B_ 64
#define T_ 576
#define C_ 768
#define SD_ 512
#define N_ 8192
#define TOK_ (B_*T_)
#define MT_ 5
#define HROWS_ 640

__device__ __forceinline__ u16 f2h(float x) {
    _Float16 v = (_Float16)x;
    return __builtin_bit_cast(u16, v);
}

// ---------------- zero scratch (count, attwh, qsumh pad rows) ----------------
__global__ void zero_kernel(unsigned int* attwh_u, unsigned int* qpad_u, int* count) {
    int i = blockIdx.x * 256 + threadIdx.x;
    if (i < 524288) attwh_u[i] = 0u;          // attwh [128][8192] f16
    if (i < 16384)  qpad_u[i]  = 0u;          // qsumh rows 64..127
    if (i < 64)     count[i]   = 0;
}

// ---------------- transpose + scale + cvt f16: dst[n][k] = g[k]*src[k][n] ----------------
__global__ __launch_bounds__(256) void transpose_cvt_kernel(
    const float* __restrict__ src, const float* __restrict__ g,
    u16* __restrict__ dst, int K, int N)
{
    __shared__ float tile[64][65];
    int k0 = blockIdx.x * 64, n0 = blockIdx.y * 64;
    int tid = threadIdx.x;
#pragma unroll
    for (int p = 0; p < 16; p++) {
        int idx = p * 256 + tid;
        int r = idx >> 6, c = idx & 63;
        float gv = g ? g[k0 + r] : 1.0f;
        tile[r][c] = src[(size_t)(k0 + r) * N + n0 + c] * gv;
    }
    __syncthreads();
#pragma unroll
    for (int p = 0; p < 16; p++) {
        int idx = p * 256 + tid;
        int r = idx >> 6, c = idx & 63;
        dst[(size_t)(n0 + r) * K + k0 + c] = f2h(tile[c][r]);
    }
}

// ---------------- plain fp32 -> f16 convert (sdh) ----------------
__global__ void cvt_plain_kernel(const float* __restrict__ src, u16* __restrict__ dst) {
    int i = blockIdx.x * 256 + threadIdx.x;      // * 8 elements
    const f32x4* s = (const f32x4*)(src + (size_t)i * 8);
    f32x4 a = s[0], b = s[1];
    u16x8 o;
    o[0]=f2h(a[0]); o[1]=f2h(a[1]); o[2]=f2h(a[2]); o[3]=f2h(a[3]);
    o[4]=f2h(b[0]); o[5]=f2h(b[1]); o[6]=f2h(b[2]); o[7]=f2h(b[3]);
    *(u16x8*)(dst + (size_t)i * 8) = o;
}

// ---------------- fold beta into bias: outp[n] = bvec[n] + sum_k beta[k]*w[k][n] ----------------
__global__ void fold_bias_kernel(const float* __restrict__ w, const float* __restrict__ bvec,
                                 const float* __restrict__ beta, float* __restrict__ outp,
                                 int K, int N)
{
    int n = blockIdx.x, l = threadIdx.x;   // 64 threads
    float s = 0.f;
    for (int k = l; k < K; k += 64) s += beta[k] * w[(size_t)k * N + n];
#pragma unroll
    for (int o = 32; o > 0; o >>= 1) s += __shfl_xor(s, o);
    if (l == 0) outp[n] = bvec[n] + s;
}

// ---------------- compact unmasked tokens per batch ----------------
__global__ void compact_kernel(const int* __restrict__ mask, int* __restrict__ list,
                               int* __restrict__ count) {
    int g = blockIdx.x * 256 + threadIdx.x;
    if (g >= TOK_) return;
    int b = g / T_, t = g % T_;
    if (mask[g] == 0) {
        int slot = atomicAdd(&count[b], 1);
        list[b * T_ + slot] = t;
    }
}

// ---------------- LN1 stats per compacted token ----------------
__global__ void ln1_stats_kernel(const float* __restrict__ ft, const int* __restrict__ list,
                                 const int* __restrict__ count, float2* __restrict__ stats1) {
    int wv = threadIdx.x >> 6, lane = threadIdx.x & 63;
    int s = blockIdx.x * 4 + wv;
    int b = s / T_, slot = s % T_;
    if (slot >= count[b]) return;
    int t = list[b * T_ + slot];
    const float4* row = (const float4*)(ft + (size_t)(b * T_ + t) * C_);
    float sum = 0.f, sq = 0.f;
#pragma unroll
    for (int p = 0; p < 3; p++) {
        float4 v = row[lane + 64 * p];
        sum += (v.x + v.y) + (v.z + v.w);
        sq  += v.x * v.x + v.y * v.y + v.z * v.z + v.w * v.w;
    }
#pragma unroll
    for (int o = 32; o > 0; o >>= 1) { sum += __shfl_xor(sum, o); sq += __shfl_xor(sq, o); }
    if (lane == 0) {
        float mu  = sum * (1.0f / C_);
        float var = fmaxf(sq * (1.0f / C_) - mu * mu, 0.0f);
        stats1[b * T_ + slot] = make_float2(mu, 1.0f / sqrtf(var + 1e-5f));
    }
}

// ---------------- GEMM1: h = GELU( LN1(ft)@w1' + b1' )  [f16 MFMA] ----------------
__global__ __launch_bounds__(256) void gemm1_kernel(
    const float* __restrict__ ft, const u16* __restrict__ w1T,
    const float* __restrict__ b1p, const int* __restrict__ list,
    const int* __restrict__ count, const float2* __restrict__ stats1,
    u16* __restrict__ h)
{
    const int b = blockIdx.x / MT_, mt = blockIdx.x % MT_;
    const int cnt = count[b];
    const int row0 = mt * 128;
    if (row0 >= cnt) return;
    const int n0 = blockIdx.y * 128;

    __shared__ __align__(16) u16 As[128 * 64];
    __shared__ __align__(16) u16 Bs[128 * 64];
    __shared__ float rmu[128], rrs[128];
    __shared__ int rtok[128];

    const int tid = threadIdx.x;
    if (tid < 128) {
        int slot = row0 + tid;
        bool v = slot < cnt;
        rtok[tid] = v ? list[b * T_ + slot] : 0;
        float2 st = v ? stats1[b * T_ + slot] : make_float2(0.f, 0.f);
        rmu[tid] = v ? st.x : 0.f;
        rrs[tid] = v ? st.y : 0.f;   // vf folded: invalid rows -> 0
    }
    __syncthreads();

    const float* aptr[4]; float amu[4], ars[4]; int adst[4];
    const u16* bptr[4];
#pragma unroll
    for (int it = 0; it < 4; it++) {
        int c = it * 256 + tid, r = c >> 3, q = c & 7;
        aptr[it] = ft + (size_t)(b * T_ + rtok[r]) * C_ + q * 8;
        amu[it] = rmu[r]; ars[it] = rrs[r];
        adst[it] = r * 64 + ((q ^ (r & 7)) << 3);
        bptr[it] = w1T + (size_t)(n0 + r) * C_ + q * 8;
    }

    const int lane = tid & 63, w = tid >> 6;
    const int wm = w >> 1, wn = w & 1;
    const int lr = lane & 15, lg = lane >> 4;
    int arow[4], brow[4];
#pragma unroll
    for (int i = 0; i < 4; i++) { arow[i] = wm * 64 + i * 16 + lr; brow[i] = wn * 64 + i * 16 + lr; }

    f32x4 pa0[4], pa1[4]; u16x8 pb[4];
#pragma unroll
    for (int it = 0; it < 4; it++) {
        pa0[it] = *(const f32x4*)(aptr[it]);
        pa1[it] = *(const f32x4*)(aptr[it] + 4);
        pb[it]  = *(const u16x8*)(bptr[it]);
    }

    f32x4 acc[4][4] = {};
    const int NKT = C_ / 64;
    for (int kt = 0; kt < NKT; kt++) {
        __syncthreads();
#pragma unroll
        for (int it = 0; it < 4; it++) {
            float mu = amu[it], rs = ars[it];
            u16x8 o;
            o[0] = f2h((pa0[it][0] - mu) * rs);
            o[1] = f2h((pa0[it][1] - mu) * rs);
            o[2] = f2h((pa0[it][2] - mu) * rs);
            o[3] = f2h((pa0[it][3] - mu) * rs);
            o[4] = f2h((pa1[it][0] - mu) * rs);
            o[5] = f2h((pa1[it][1] - mu) * rs);
            o[6] = f2h((pa1[it][2] - mu) * rs);
            o[7] = f2h((pa1[it][3] - mu) * rs);
            *(u16x8*)&As[adst[it]] = o;
            *(u16x8*)&Bs[adst[it]] = pb[it];
        }
        __syncthreads();
        if (kt + 1 < NKT) {
            int k = (kt + 1) * 64;
#pragma unroll
            for (int it = 0; it < 4; it++) {
                pa0[it] = *(const f32x4*)(aptr[it] + k);
                pa1[it] = *(const f32x4*)(aptr[it] + k + 4);
                pb[it]  = *(const u16x8*)(bptr[it] + k);
            }
        }
#pragma unroll
        for (int ks = 0; ks < 4; ks++) {
            int kq = ks * 4 + lg;
            int qo = kq >> 1, ho = (kq & 1) << 2;
            half4 aF[4], bF[4];
#pragma unroll
            for (int i = 0; i < 4; i++)
                aF[i] = *(const half4*)&As[arow[i] * 64 + ((qo ^ (arow[i] & 7)) << 3) + ho];
#pragma unroll
            for (int i = 0; i < 4; i++)
                bF[i] = *(const half4*)&Bs[brow[i] * 64 + ((qo ^ (brow[i] & 7)) << 3) + ho];
#pragma unroll
            for (int mi = 0; mi < 4; mi++)
#pragma unroll
                for (int ni = 0; ni < 4; ni++)
                    acc[mi][ni] = __builtin_amdgcn_mfma_f32_16x16x16f16(aF[mi], bF[ni], acc[mi][ni], 0, 0, 0);
        }
    }

    float bb[4];
#pragma unroll
    for (int ni = 0; ni < 4; ni++) bb[ni] = b1p[n0 + wn * 64 + ni * 16 + lr];
#pragma unroll
    for (int mi = 0; mi < 4; mi++) {
#pragma unroll
        for (int r = 0; r < 4; r++) {
            int grow = row0 + wm * 64 + mi * 16 + 4 * lg + r;
            u16* hp = h + (size_t)(b * HROWS_ + grow) * SD_ + n0 + wn * 64 + lr;
#pragma unroll
            for (int ni = 0; ni < 4; ni++) {
                float x = acc[mi][ni][r] + bb[ni];
                float gel = 0.5f * x * (1.0f + erff(x * 0.70710678118654752f));
                hp[ni * 16] = f2h(gel);
            }
        }
    }
}

// ---------------- LN2 stats over h rows (f16) ----------------
__global__ void ln2_stats_kernel(const u16* __restrict__ h, const int* __restrict__ count,
                                 float2* __restrict__ stats2) {
    int wv = threadIdx.x >> 6, lane = threadIdx.x & 63;
    int s = blockIdx.x * 4 + wv;
    int b = s / T_, slot = s % T_;
    if (slot >= count[b]) return;
    const half8* row = (const half8*)(h + (size_t)(b * HROWS_ + slot) * SD_);
    half8 v = row[lane];
    float sum = 0.f, sq = 0.f;
#pragma unroll
    for (int j = 0; j < 8; j++) { float f = (float)v[j]; sum += f; sq += f * f; }
#pragma unroll
    for (int o = 32; o > 0; o >>= 1) { sum += __shfl_xor(sum, o); sq += __shfl_xor(sq, o); }
    if (lane == 0) {
        float mu  = sum * (1.0f / SD_);
        float var = fmaxf(sq * (1.0f / SD_) - mu * mu, 0.0f);
        stats2[b * T_ + slot] = make_float2(mu, 1.0f / sqrtf(var + 1e-5f));
    }
}

// ---------------- GEMM2: column-sums of LN2(h)@w2'  [f16 MFMA] ----------------
__global__ __launch_bounds__(256) void gemm2_kernel(
    const u16* __restrict__ h, const u16* __restrict__ w2T,
    const int* __restrict__ count, const float2* __restrict__ stats2,
    float* __restrict__ partial)
{
    const int b = blockIdx.x / MT_, mt = blockIdx.x % MT_;
    const int cnt = count[b];
    const int row0 = mt * 128;
    if (row0 >= cnt) return;
    const int n0 = blockIdx.y * 128;

    __shared__ __align__(16) u16 As[128 * 64];
    __shared__ __align__(16) u16 Bs[128 * 64];
    __shared__ float rmu[128], rrs[128];
    __shared__ float redbuf[4][64];

    const int tid = threadIdx.x;
    if (tid < 128) {
        int slot = row0 + tid;
        bool v = slot < cnt;
        float2 st = v ? stats2[b * T_ + slot] : make_float2(0.f, 0.f);
        rmu[tid] = v ? st.x : 0.f;
        rrs[tid] = v ? st.y : 0.f;
    }
    __syncthreads();

    const u16* aptr[4]; float amu[4], ars[4]; int adst[4];
    const u16* bptr[4];
#pragma unroll
    for (int it = 0; it < 4; it++) {
        int c = it * 256 + tid, r = c >> 3, q = c & 7;
        aptr[it] = h + (size_t)(b * HROWS_ + row0 + r) * SD_ + q * 8;
        amu[it] = rmu[r]; ars[it] = rrs[r];
        adst[it] = r * 64 + ((q ^ (r & 7)) << 3);
        bptr[it] = w2T + (size_t)(n0 + r) * SD_ + q * 8;
    }

    const int lane = tid & 63, w = tid >> 6;
    const int wm = w >> 1, wn = w & 1;
    const int lr = lane & 15, lg = lane >> 4;
    int arow[4], brow[4];
#pragma unroll
    for (int i = 0; i < 4; i++) { arow[i] = wm * 64 + i * 16 + lr; brow[i] = wn * 64 + i * 16 + lr; }

    u16x8 pa[4], pb[4];
#pragma unroll
    for (int it = 0; it < 4; it++) {
        pa[it] = *(const u16x8*)(aptr[it]);
        pb[it] = *(const u16x8*)(bptr[it]);
    }

    f32x4 acc[4][4] = {};
    const int NKT = SD_ / 64;
    for (int kt = 0; kt < NKT; kt++) {
        __syncthreads();
#pragma unroll
        for (int it = 0; it < 4; it++) {
            float mu = amu[it], rs = ars[it];
            half8 hv = __builtin_bit_cast(half8, pa[it]);
            u16x8 o;
#pragma unroll
            for (int j = 0; j < 8; j++) o[j] = f2h(((float)hv[j] - mu) * rs);
            *(u16x8*)&As[adst[it]] = o;
            *(u16x8*)&Bs[adst[it]] = pb[it];
        }
        __syncthreads();
        if (kt + 1 < NKT) {
            int k = (kt + 1) * 64;
#pragma unroll
            for (int it = 0; it < 4; it++) {
                pa[it] = *(const u16x8*)(aptr[it] + k);
                pb[it] = *(const u16x8*)(bptr[it] + k);
            }
        }
#pragma unroll
        for (int ks = 0; ks < 4; ks++) {
            int kq = ks * 4 + lg;
            int qo = kq >> 1, ho = (kq & 1) << 2;
            half4 aF[4], bF[4];
#pragma unroll
            for (int i = 0; i < 4; i++)
                aF[i] = *(const half4*)&As[arow[i] * 64 + ((qo ^ (arow[i] & 7)) << 3) + ho];
#pragma unroll
            for (int i = 0; i < 4; i++)
                bF[i] = *(const half4*)&Bs[brow[i] * 64 + ((qo ^ (brow[i] & 7)) << 3) + ho];
#pragma unroll
            for (int mi = 0; mi < 4; mi++)
#pragma unroll
                for (int ni = 0; ni < 4; ni++)
                    acc[mi][ni] = __builtin_amdgcn_mfma_f32_16x16x16f16(aF[mi], bF[ni], acc[mi][ni], 0, 0, 0);
        }
    }

    float s[4];
#pragma unroll
    for (int ni = 0; ni < 4; ni++) {
        float t = 0.f;
#pragma unroll
        for (int mi = 0; mi < 4; mi++)
#pragma unroll
            for (int r = 0; r < 4; r++) t += acc[mi][ni][r];
        t += __shfl_xor(t, 16);
        t += __shfl_xor(t, 32);
        s[ni] = t;
    }
    if (lane < 16) {
#pragma unroll
        for (int ni = 0; ni < 4; ni++) redbuf[w][ni * 16 + lr] = s[ni];
    }
    __syncthreads();
    if (tid < 128) {
        int wn2 = tid >> 6, idx = tid & 63;
        float v = redbuf[wn2][idx] + redbuf[wn2 + 2][idx];
        partial[(size_t)(b * MT_ + mt) * SD_ + n0 + tid] = v;
    }
}

// ---------------- qsum (f16) = (sum partials + cnt*b2') / sqrt(512) ----------------
__global__ void qsum_reduce_kernel(const float* __restrict__ partial, const int* __restrict__ count,
                                   const float* __restrict__ b2p, u16* __restrict__ qsumh) {
    int i = blockIdx.x * 256 + threadIdx.x;    // 32768
    int b = i >> 9, d = i & 511;
    int cnt = count[b];
    int mts = (cnt + 127) >> 7;
    float s = 0.f;
    for (int mt = 0; mt < mts; mt++) s += partial[(size_t)(b * MT_ + mt) * SD_ + d];
    s = (s + (float)cnt * b2p[d]) * 0.04419417382415922f;
    qsumh[i] = f2h(s);
}

// ---------------- generic plain f16 GEMM (pooled / att_ft) ----------------
__global__ __launch_bounds__(256) void gemm_plain_kernel(
    const u16* __restrict__ A, int ldA,
    const u16* __restrict__ BT, int ldBT,
    float* __restrict__ C, int ldC, int nkt)
{
    const int kz = blockIdx.x, nt = blockIdx.y;
    const int n0 = nt * 128;
    const int kbase = kz * nkt * 64;

    __shared__ __align__(16) u16 As[128 * 64];
    __shared__ __align__(16) u16 Bs[128 * 64];

    const int tid = threadIdx.x;
    const u16* aptr[4]; const u16* bptr[4]; int adst[4];
#pragma unroll
    for (int it = 0; it < 4; it++) {
        int c = it * 256 + tid, r = c >> 3, q = c & 7;
        aptr[it] = A  + (size_t)r * ldA + kbase + q * 8;
        bptr[it] = BT + (size_t)(n0 + r) * ldBT + kbase + q * 8;
        adst[it] = r * 64 + ((q ^ (r & 7)) << 3);
    }

    const int lane = tid & 63, w = tid >> 6;
    const int wm = w >> 1, wn = w & 1;
    const int lr = lane & 15, lg = lane >> 4;
    int arow[4], brow[4];
#pragma unroll
    for (int i = 0; i < 4; i++) { arow[i] = wm * 64 + i * 16 + lr; brow[i] = wn * 64 + i * 16 + lr; }

    u16x8 pa[4], pb[4];
#pragma unroll
    for (int it = 0; it < 4; it++) {
        pa[it] = *(const u16x8*)(aptr[it]);
        pb[it] = *(const u16x8*)(bptr[it]);
    }

    f32x4 acc[4][4] = {};
    for (int kt = 0; kt < nkt; kt++) {
        __syncthreads();
#pragma unroll
        for (int it = 0; it < 4; it++) {
            *(u16x8*)&As[adst[it]] = pa[it];
            *(u16x8*)&Bs[adst[it]] = pb[it];
        }
        __syncthreads();
        if (kt + 1 < nkt) {
            int k = (kt + 1) * 64;
#pragma unroll
            for (int it = 0; it < 4; it++) {
                pa[it] = *(const u16x8*)(aptr[it] + k);
                pb[it] = *(const u16x8*)(bptr[it] + k);
            }
        }
#pragma unroll
        for (int ks = 0; ks < 4; ks++) {
            int kq = ks * 4 + lg;
            int qo = kq >> 1, ho = (kq & 1) << 2;
            half4 aF[4], bF[4];
#pragma unroll
            for (int i = 0; i < 4; i++)
                aF[i] = *(const half4*)&As[arow[i] * 64 + ((qo ^ (arow[i] & 7)) << 3) + ho];
#pragma unroll
            for (int i = 0; i < 4; i++)
                bF[i] = *(const half4*)&Bs[brow[i] * 64 + ((qo ^ (brow[i] & 7)) << 3) + ho];
#pragma unroll
            for (int mi = 0; mi < 4; mi++)
#pragma unroll
                for (int ni = 0; ni < 4; ni++)
                    acc[mi][ni] = __builtin_amdgcn_mfma_f32_16x16x16f16(aF[mi], bF[ni], acc[mi][ni], 0, 0, 0);
        }
    }

    float* Cb = C + (size_t)kz * 128 * ldC + n0;
#pragma unroll
    for (int mi = 0; mi < 4; mi++)
#pragma unroll
        for (int r = 0; r < 4; r++) {
            int grow = wm * 64 + mi * 16 + 4 * lg + r;
#pragma unroll
            for (int ni = 0; ni < 4; ni++)
                Cb[(size_t)grow * ldC + wn * 64 + ni * 16 + lr] = acc[mi][ni][r];
        }
}

// ---------------- softmax per batch row ----------------
__global__ __launch_bounds__(256) void softmax_kernel(const float* __restrict__ pooled,
                                                      float* __restrict__ attw,
                                                      u16* __restrict__ attwh) {
    __shared__ float rowm[N_];
    __shared__ float red[4];
    int b = blockIdx.x, tid = threadIdx.x;
    const float4* src = (const float4*)(pooled + (size_t)b * N_);
    float mx = -3.4e38f;
#pragma unroll
    for (int p = 0; p < 8; p++) {
        float4 v = src[tid + 256 * p];
        *((float4*)&rowm[(tid + 256 * p) * 4]) = v;
        mx = fmaxf(fmaxf(fmaxf(v.x, v.y), fmaxf(v.z, v.w)), mx);
    }
#pragma unroll
    for (int o = 32; o > 0; o >>= 1) mx = fmaxf(mx, __shfl_xor(mx, o));
    if ((tid & 63) == 0) red[tid >> 6] = mx;
    __syncthreads();
    mx = fmaxf(fmaxf(red[0], red[1]), fmaxf(red[2], red[3]));
    __syncthreads();
    float s = 0.f;
    for (int p = 0; p < 8; p++) {
        int i4 = tid + 256 * p;
        float4 v = *((float4*)&rowm[i4 * 4]);
        v.x = expf(v.x - mx); v.y = expf(v.y - mx);
        v.z = expf(v.z - mx); v.w = expf(v.w - mx);
        *((float4*)&rowm[i4 * 4]) = v;
        s += (v.x + v.y) + (v.z + v.w);
    }
#pragma unroll
    for (int o = 32; o > 0; o >>= 1) s += __shfl_xor(s, o);
    if ((tid & 63) == 0) red[tid >> 6] = s;
    __syncthreads();
    s = ((red[0] + red[1]) + (red[2] + red[3]));
    float inv = 1.0f / s;
    float4* dst = (float4*)(attw + (size_t)b * N_);
    u16* dh = attwh + (size_t)b * N_;
    for (int p = 0; p < 8; p++) {
        int i4 = tid + 256 * p;
        float4 v = *((float4*)&rowm[i4 * 4]);
        v.x *= inv; v.y *= inv; v.z *= inv; v.w *= inv;
        dst[i4] = v;
        ushort4 pk;
        pk.x = f2h(v.x); pk.y = f2h(v.y); pk.z = f2h(v.z); pk.w = f2h(v.w);
        *(ushort4*)(dh + (size_t)i4 * 4) = pk;
    }
}

// ---------------- att_ft reduce over K-splits ----------------
__global__ void attft_reduce_kernel(const float* __restrict__ p2, float* __restrict__ att_ft) {
    int i = blockIdx.x * 256 + threadIdx.x;    // 32768
    int b = i >> 9, d = i & 511;
    float s = 0.f;
#pragma unroll
    for (int kz = 0; kz < 8; kz++) s += p2[(size_t)kz * 128 * SD_ + (size_t)b * SD_ + d];
    att_ft[i] = s;
}

extern "C" void kernel_launch(void* const* d_in, const int* in_sizes, int n_in,
                              void* d_out, int out_size, void* d_ws, size_t ws_size,
                              hipStream_t stream) {
    (void)in_sizes; (void)n_in; (void)out_size; (void)ws_size;
    const float* ft  = (const float*)d_in[0];
    const float* sd  = (const float*)d_in[1];
    const int*   mask= (const int*)d_in[2];
    const float* g1  = (const float*)d_in[3];
    const float* bl1 = (const float*)d_in[4];
    const float* w1  = (const float*)d_in[5];
    const float* b1  = (const float*)d_in[6];
    const float* g2  = (const float*)d_in[7];
    const float* bl2 = (const float*)d_in[8];
    const float* w2  = (const float*)d_in[9];
    const float* b2  = (const float*)d_in[10];
    float* out = (float*)d_out;
    char* W = (char*)d_ws;

    u16*    w1T    = (u16*)(W + 0);
    u16*    w2T    = (u16*)(W + 786432);
    u16*    sdh    = (u16*)(W + 1310720);
    u16*    sdT    = (u16*)(W + 9699328);
    float*  b1p    = (float*)(W + 18087936);
    float*  b2p    = (float*)(W + 18089984);
    int*    list   = (int*)(W + 18092032);
    int*    count  = (int*)(W + 18239488);
    float2* st1    = (float2*)(W + 18239744);
    float2* st2    = (float2*)(W + 18534656);
    u16*    h      = (u16*)(W + 18829568);
    float*  partial= (float*)(W + 60772608);
    u16*    qsumh  = (u16*)(W + 61427968);
    float*  pooled = (float*)(W + 61559040);
    u16*    attwh  = (u16*)(W + 65753344);
    float*  p2     = (float*)(W + 67850496);

    float* att_w  = out;
    float* att_ft = out + (size_t)B_ * N_;
    float* sd_out = out + (size_t)B_ * N_ + (size_t)B_ * SD_;

    zero_kernel<<<2048, 256, 0, stream>>>((unsigned int*)attwh, (unsigned int*)(qsumh + 64 * SD_), count);
    transpose_cvt_kernel<<<dim3(C_ / 64, SD_ / 64), 256, 0, stream>>>(w1, g1, w1T, C_, SD_);
    transpose_cvt_kernel<<<dim3(SD_ / 64, SD_ / 64), 256, 0, stream>>>(w2, g2, w2T, SD_, SD_);
    transpose_cvt_kernel<<<dim3(N_ / 64, SD_ / 64), 256, 0, stream>>>(sd, nullptr, sdT, N_, SD_);
    cvt_plain_kernel<<<2048, 256, 0, stream>>>(sd, sdh);
    fold_bias_kernel<<<SD_, 64, 0, stream>>>(w1, b1, bl1, b1p, C_, SD_);
    fold_bias_kernel<<<SD_, 64, 0, stream>>>(w2, b2, bl2, b2p, SD_, SD_);
    compact_kernel<<<144, 256, 0, stream>>>(mask, list, count);
    ln1_stats_kernel<<<TOK_ / 4, 256, 0, stream>>>(ft, list, count, st1);
    gemm1_kernel<<<dim3(B_ * MT_, 4), 256, 0, stream>>>(ft, w1T, b1p, list, count, st1, h);
    ln2_stats_kernel<<<TOK_ / 4, 256, 0, stream>>>(h, count, st2);
    gemm2_kernel<<<dim3(B_ * MT_, 4), 256, 0, stream>>>(h, w2T, count, st2, partial);
    qsum_reduce_kernel<<<128, 256, 0, stream>>>(partial, count, b2p, qsumh);
    gemm_plain_kernel<<<dim3(1, 64), 256, 0, stream>>>(qsumh, SD_, sdh, SD_, pooled, N_, 8);
    softmax_kernel<<<B_, 256, 0, stream>>>(pooled, att_w, attwh);
    gemm_plain_kernel<<<dim3(8, 4), 256, 0, stream>>>(attwh, N_, sdT, N_, p2, SD_, 16);
    attft_reduce_kernel<<<128, 256, 0, stream>>>(p2, att_ft);
    hipMemcpyAsync(sd_out, sd, (size_t)N_ * SD_ * sizeof(float), hipMemcpyDeviceToDevice, stream);
}

// Round 5
// 438.608 us; speedup vs baseline: 1.6713x; 1.0820x over previous
//
#include <hip/hip_runtime.h>
#include <math.h>

typedef unsigned short u16;
typedef _Float16 half8 __attribute__((ext_vector_type(8)));
typedef float f32x4 __attribute__((ext_vector_type(4)));
typedef u16 u16x8 __attribute__((ext_vector_type(8)));

#define B_ 64
#define T_ 576
#define C_ 768
#define SD_ 512
#define N_ 8192
#define TOK_ (B_*T_)
#define MT_ 5
#define HROWS_ 640

__device__ __forceinline__ u16 f2h(float x) {
    _Float16 v = (_Float16)x;
    return __builtin_bit_cast(u16, v);
}

// ---------------- zero scratch (count, attwh, qsumh pad rows) ----------------
__global__ void zero_kernel(unsigned int* attwh_u, unsigned int* qpad_u, int* count) {
    int i = blockIdx.x * 256 + threadIdx.x;
    if (i < 524288) attwh_u[i] = 0u;          // attwh [128][8192] f16
    if (i < 16384)  qpad_u[i]  = 0u;          // qsumh rows 64..127
    if (i < 64)     count[i]   = 0;
}

// ---------------- transpose + scale + cvt f16: dst[n][k] = g[k]*src[k][n] ----------------
__global__ __launch_bounds__(256) void transpose_cvt_kernel(
    const float* __restrict__ src, const float* __restrict__ g,
    u16* __restrict__ dst, int K, int N)
{
    __shared__ float tile[64][65];
    int k0 = blockIdx.x * 64, n0 = blockIdx.y * 64;
    int tid = threadIdx.x;
#pragma unroll
    for (int p = 0; p < 16; p++) {
        int idx = p * 256 + tid;
        int r = idx >> 6, c = idx & 63;
        float gv = g ? g[k0 + r] : 1.0f;
        tile[r][c] = src[(size_t)(k0 + r) * N + n0 + c] * gv;
    }
    __syncthreads();
#pragma unroll
    for (int p = 0; p < 16; p++) {
        int idx = p * 256 + tid;
        int r = idx >> 6, c = idx & 63;
        dst[(size_t)(n0 + r) * K + k0 + c] = f2h(tile[c][r]);
    }
}

// ---------------- sd prep: sdh = f16(sd), sdT = f16(sd^T), one read of sd ----------------
__global__ __launch_bounds__(256) void sd_prep_kernel(
    const float* __restrict__ sd, u16* __restrict__ sdh, u16* __restrict__ sdT)
{
    __shared__ float tile[64][65];
    int k0 = blockIdx.x * 64, n0 = blockIdx.y * 64;   // k over 8192 rows, n over 512 cols
    int tid = threadIdx.x;
#pragma unroll
    for (int p = 0; p < 16; p++) {
        int idx = p * 256 + tid;
        int r = idx >> 6, c = idx & 63;
        float v = sd[(size_t)(k0 + r) * SD_ + n0 + c];
        tile[r][c] = v;
        sdh[(size_t)(k0 + r) * SD_ + n0 + c] = f2h(v);
    }
    __syncthreads();
#pragma unroll
    for (int p = 0; p < 16; p++) {
        int idx = p * 256 + tid;
        int r = idx >> 6, c = idx & 63;
        sdT[(size_t)(n0 + r) * N_ + k0 + c] = f2h(tile[c][r]);
    }
}

// ---------------- fold beta into bias: outp[n] = bvec[n] + sum_k beta[k]*w[k][n] ----------------
__global__ void fold_bias_kernel(const float* __restrict__ w, const float* __restrict__ bvec,
                                 const float* __restrict__ beta, float* __restrict__ outp,
                                 int K, int N)
{
    int n = blockIdx.x, l = threadIdx.x;   // 64 threads
    float s = 0.f;
    for (int k = l; k < K; k += 64) s += beta[k] * w[(size_t)k * N + n];
#pragma unroll
    for (int o = 32; o > 0; o >>= 1) s += __shfl_xor(s, o);
    if (l == 0) outp[n] = bvec[n] + s;
}

// ---------------- compact unmasked tokens per batch ----------------
__global__ void compact_kernel(const int* __restrict__ mask, int* __restrict__ list,
                               int* __restrict__ count) {
    int g = blockIdx.x * 256 + threadIdx.x;
    if (g >= TOK_) return;
    int b = g / T_, t = g % T_;
    if (mask[g] == 0) {
        int slot = atomicAdd(&count[b], 1);
        list[b * T_ + slot] = t;
    }
}

// ---------------- LN1 stats per compacted token ----------------
__global__ void ln1_stats_kernel(const float* __restrict__ ft, const int* __restrict__ list,
                                 const int* __restrict__ count, float2* __restrict__ stats1) {
    int wv = threadIdx.x >> 6, lane = threadIdx.x & 63;
    int s = blockIdx.x * 4 + wv;
    int b = s / T_, slot = s % T_;
    if (slot >= count[b]) return;
    int t = list[b * T_ + slot];
    const float4* row = (const float4*)(ft + (size_t)(b * T_ + t) * C_);
    float sum = 0.f, sq = 0.f;
#pragma unroll
    for (int p = 0; p < 3; p++) {
        float4 v = row[lane + 64 * p];
        sum += (v.x + v.y) + (v.z + v.w);
        sq  += v.x * v.x + v.y * v.y + v.z * v.z + v.w * v.w;
    }
#pragma unroll
    for (int o = 32; o > 0; o >>= 1) { sum += __shfl_xor(sum, o); sq += __shfl_xor(sq, o); }
    if (lane == 0) {
        float mu  = sum * (1.0f / C_);
        float var = fmaxf(sq * (1.0f / C_) - mu * mu, 0.0f);
        stats1[b * T_ + slot] = make_float2(mu, 1.0f / sqrtf(var + 1e-5f));
    }
}

// ---------------- GEMM1: h = GELU( LN1(ft)@w1' + b1' ), K=32 MFMA, + row stats ----------------
__global__ __launch_bounds__(256) void gemm1_kernel(
    const float* __restrict__ ft, const u16* __restrict__ w1T,
    const float* __restrict__ b1p, const int* __restrict__ list,
    const int* __restrict__ count, const float2* __restrict__ stats1,
    u16* __restrict__ h, float* __restrict__ rstat)
{
    const int b = blockIdx.x / MT_, mt = blockIdx.x % MT_;
    const int cnt = count[b];
    const int row0 = mt * 128;
    if (row0 >= cnt) return;
    const int n0 = blockIdx.y * 128;

    __shared__ __align__(16) u16 As[128 * 64];
    __shared__ __align__(16) u16 Bs[128 * 64];
    __shared__ float rmu[128], rrs[128];
    __shared__ int rtok[128];

    const int tid = threadIdx.x;
    if (tid < 128) {
        int slot = row0 + tid;
        bool v = slot < cnt;
        rtok[tid] = v ? list[b * T_ + slot] : 0;
        float2 st = v ? stats1[b * T_ + slot] : make_float2(0.f, 0.f);
        rmu[tid] = v ? st.x : 0.f;
        rrs[tid] = v ? st.y : 0.f;   // invalid rows -> A row = 0
    }
    __syncthreads();

    const float* aptr[4]; float amu[4], ars[4]; int adst[4];
    const u16* bptr[4];
#pragma unroll
    for (int it = 0; it < 4; it++) {
        int c = it * 256 + tid, r = c >> 3, q = c & 7;
        aptr[it] = ft + (size_t)(b * T_ + rtok[r]) * C_ + q * 8;
        amu[it] = rmu[r]; ars[it] = rrs[r];
        adst[it] = r * 64 + ((q ^ (r & 7)) << 3);
        bptr[it] = w1T + (size_t)(n0 + r) * C_ + q * 8;
    }

    const int lane = tid & 63, w = tid >> 6;
    const int wm = w >> 1, wn = w & 1;
    const int lr = lane & 15, lg = lane >> 4;
    int arow[4], brow[4];
#pragma unroll
    for (int i = 0; i < 4; i++) { arow[i] = wm * 64 + i * 16 + lr; brow[i] = wn * 64 + i * 16 + lr; }

    f32x4 pa0[4], pa1[4]; u16x8 pb[4];
#pragma unroll
    for (int it = 0; it < 4; it++) {
        pa0[it] = *(const f32x4*)(aptr[it]);
        pa1[it] = *(const f32x4*)(aptr[it] + 4);
        pb[it]  = *(const u16x8*)(bptr[it]);
    }

    f32x4 acc[4][4] = {};
    const int NKT = C_ / 64;
    for (int kt = 0; kt < NKT; kt++) {
        __syncthreads();
#pragma unroll
        for (int it = 0; it < 4; it++) {
            float mu = amu[it], rs = ars[it];
            u16x8 o;
            o[0] = f2h((pa0[it][0] - mu) * rs);
            o[1] = f2h((pa0[it][1] - mu) * rs);
            o[2] = f2h((pa0[it][2] - mu) * rs);
            o[3] = f2h((pa0[it][3] - mu) * rs);
            o[4] = f2h((pa1[it][0] - mu) * rs);
            o[5] = f2h((pa1[it][1] - mu) * rs);
            o[6] = f2h((pa1[it][2] - mu) * rs);
            o[7] = f2h((pa1[it][3] - mu) * rs);
            *(u16x8*)&As[adst[it]] = o;
            *(u16x8*)&Bs[adst[it]] = pb[it];
        }
        __syncthreads();
        if (kt + 1 < NKT) {
            int k = (kt + 1) * 64;
#pragma unroll
            for (int it = 0; it < 4; it++) {
                pa0[it] = *(const f32x4*)(aptr[it] + k);
                pa1[it] = *(const f32x4*)(aptr[it] + k + 4);
                pb[it]  = *(const u16x8*)(bptr[it] + k);
            }
        }
#pragma unroll
        for (int ks = 0; ks < 2; ks++) {
            half8 aF[4], bF[4];
#pragma unroll
            for (int i = 0; i < 4; i++) {
                int ra = arow[i];
                aF[i] = *(const half8*)&As[ra * 64 + (((ks * 4 + lg) ^ (ra & 7)) << 3)];
            }
#pragma unroll
            for (int i = 0; i < 4; i++) {
                int rb = brow[i];
                bF[i] = *(const half8*)&Bs[rb * 64 + (((ks * 4 + lg) ^ (rb & 7)) << 3)];
            }
#pragma unroll
            for (int mi = 0; mi < 4; mi++)
#pragma unroll
                for (int ni = 0; ni < 4; ni++)
                    acc[mi][ni] = __builtin_amdgcn_mfma_f32_16x16x32_f16(aF[mi], bF[ni], acc[mi][ni], 0, 0, 0);
        }
    }

    float bb[4];
#pragma unroll
    for (int ni = 0; ni < 4; ni++) bb[ni] = b1p[n0 + wn * 64 + ni * 16 + lr];
#pragma unroll
    for (int mi = 0; mi < 4; mi++) {
#pragma unroll
        for (int r = 0; r < 4; r++) {
            int grow = row0 + wm * 64 + mi * 16 + 4 * lg + r;
            u16* hp = h + (size_t)(b * HROWS_ + grow) * SD_ + n0 + wn * 64 + lr;
            float s = 0.f, q = 0.f;
#pragma unroll
            for (int ni = 0; ni < 4; ni++) {
                float x = acc[mi][ni][r] + bb[ni];
                float gel = 0.5f * x * (1.0f + erff(x * 0.70710678118654752f));
                hp[ni * 16] = f2h(gel);
                s += gel; q += gel * gel;
            }
            // reduce 64-col partial over the 16 lr lanes (lg bits preserved)
            s += __shfl_xor(s, 1); s += __shfl_xor(s, 2); s += __shfl_xor(s, 4); s += __shfl_xor(s, 8);
            q += __shfl_xor(q, 1); q += __shfl_xor(q, 2); q += __shfl_xor(q, 4); q += __shfl_xor(q, 8);
            if (lr == 0) {
                float* rp = rstat + ((size_t)((blockIdx.y * 2 + wn) * B_ + b) * HROWS_ + grow) * 2;
                rp[0] = s; rp[1] = q;
            }
        }
    }
}

// ---------------- GEMM2: column-sums of LN2(h)@w2', K=32 MFMA, stats from rstat ----------------
__global__ __launch_bounds__(256) void gemm2_kernel(
    const u16* __restrict__ h, const u16* __restrict__ w2T,
    const int* __restrict__ count, const float* __restrict__ rstat,
    float* __restrict__ partial)
{
    const int b = blockIdx.x / MT_, mt = blockIdx.x % MT_;
    const int cnt = count[b];
    const int row0 = mt * 128;
    if (row0 >= cnt) return;
    const int n0 = blockIdx.y * 128;

    __shared__ __align__(16) u16 As[128 * 64];
    __shared__ __align__(16) u16 Bs[128 * 64];
    __shared__ float rmu[128], rrs[128];
    __shared__ float redbuf[4][64];

    const int tid = threadIdx.x;
    if (tid < 128) {
        int slot = row0 + tid;
        bool v = slot < cnt;
        float mu = 0.f, rs = 0.f;
        if (v) {
            float s = 0.f, q = 0.f;
            size_t ro = (size_t)(row0 + tid) * 2;
#pragma unroll
            for (int p = 0; p < 8; p++) {
                const float* rp = rstat + ((size_t)(p * B_ + b) * HROWS_) * 2 + ro;
                s += rp[0]; q += rp[1];
            }
            mu = s * (1.0f / SD_);
            float var = fmaxf(q * (1.0f / SD_) - mu * mu, 0.0f);
            rs = 1.0f / sqrtf(var + 1e-5f);
        }
        rmu[tid] = mu; rrs[tid] = rs;
    }
    __syncthreads();

    const u16* aptr[4]; float amu[4], ars[4]; int adst[4];
    const u16* bptr[4];
#pragma unroll
    for (int it = 0; it < 4; it++) {
        int c = it * 256 + tid, r = c >> 3, q = c & 7;
        aptr[it] = h + (size_t)(b * HROWS_ + row0 + r) * SD_ + q * 8;
        amu[it] = rmu[r]; ars[it] = rrs[r];
        adst[it] = r * 64 + ((q ^ (r & 7)) << 3);
        bptr[it] = w2T + (size_t)(n0 + r) * SD_ + q * 8;
    }

    const int lane = tid & 63, w = tid >> 6;
    const int wm = w >> 1, wn = w & 1;
    const int lr = lane & 15, lg = lane >> 4;
    int arow[4], brow[4];
#pragma unroll
    for (int i = 0; i < 4; i++) { arow[i] = wm * 64 + i * 16 + lr; brow[i] = wn * 64 + i * 16 + lr; }

    u16x8 pa[4], pb[4];
#pragma unroll
    for (int it = 0; it < 4; it++) {
        pa[it] = *(const u16x8*)(aptr[it]);
        pb[it] = *(const u16x8*)(bptr[it]);
    }

    f32x4 acc[4][4] = {};
    const int NKT = SD_ / 64;
    for (int kt = 0; kt < NKT; kt++) {
        __syncthreads();
#pragma unroll
        for (int it = 0; it < 4; it++) {
            float mu = amu[it], rs = ars[it];
            u16x8 o;
#pragma unroll
            for (int j = 0; j < 8; j++) {
                _Float16 hv = __builtin_bit_cast(_Float16, (u16)pa[it][j]);
                o[j] = f2h(((float)hv - mu) * rs);
            }
            *(u16x8*)&As[adst[it]] = o;
            *(u16x8*)&Bs[adst[it]] = pb[it];
        }
        __syncthreads();
        if (kt + 1 < NKT) {
            int k = (kt + 1) * 64;
#pragma unroll
            for (int it = 0; it < 4; it++) {
                pa[it] = *(const u16x8*)(aptr[it] + k);
                pb[it] = *(const u16x8*)(bptr[it] + k);
            }
        }
#pragma unroll
        for (int ks = 0; ks < 2; ks++) {
            half8 aF[4], bF[4];
#pragma unroll
            for (int i = 0; i < 4; i++) {
                int ra = arow[i];
                aF[i] = *(const half8*)&As[ra * 64 + (((ks * 4 + lg) ^ (ra & 7)) << 3)];
            }
#pragma unroll
            for (int i = 0; i < 4; i++) {
                int rb = brow[i];
                bF[i] = *(const half8*)&Bs[rb * 64 + (((ks * 4 + lg) ^ (rb & 7)) << 3)];
            }
#pragma unroll
            for (int mi = 0; mi < 4; mi++)
#pragma unroll
                for (int ni = 0; ni < 4; ni++)
                    acc[mi][ni] = __builtin_amdgcn_mfma_f32_16x16x32_f16(aF[mi], bF[ni], acc[mi][ni], 0, 0, 0);
        }
    }

    float s[4];
#pragma unroll
    for (int ni = 0; ni < 4; ni++) {
        float t = 0.f;
#pragma unroll
        for (int mi = 0; mi < 4; mi++)
#pragma unroll
            for (int r = 0; r < 4; r++) t += acc[mi][ni][r];
        t += __shfl_xor(t, 16);
        t += __shfl_xor(t, 32);
        s[ni] = t;
    }
    if (lane < 16) {
#pragma unroll
        for (int ni = 0; ni < 4; ni++) redbuf[w][ni * 16 + lr] = s[ni];
    }
    __syncthreads();
    if (tid < 128) {
        int wn2 = tid >> 6, idx = tid & 63;
        float v = redbuf[wn2][idx] + redbuf[wn2 + 2][idx];
        partial[(size_t)(b * MT_ + mt) * SD_ + n0 + tid] = v;
    }
}

// ---------------- qsum (f16) = (sum partials + cnt*b2') / sqrt(512) ----------------
__global__ void qsum_reduce_kernel(const float* __restrict__ partial, const int* __restrict__ count,
                                   const float* __restrict__ b2p, u16* __restrict__ qsumh) {
    int i = blockIdx.x * 256 + threadIdx.x;    // 32768
    int b = i >> 9, d = i & 511;
    int cnt = count[b];
    int mts = (cnt + 127) >> 7;
    float s = 0.f;
    for (int mt = 0; mt < mts; mt++) s += partial[(size_t)(b * MT_ + mt) * SD_ + d];
    s = (s + (float)cnt * b2p[d]) * 0.04419417382415922f;
    qsumh[i] = f2h(s);
}

// ---------------- generic plain f16 GEMM (pooled / att_ft), K=32 MFMA ----------------
__global__ __launch_bounds__(256) void gemm_plain_kernel(
    const u16* __restrict__ A, int ldA,
    const u16* __restrict__ BT, int ldBT,
    float* __restrict__ C, int ldC, int nkt)
{
    const int kz = blockIdx.x, nt = blockIdx.y;
    const int n0 = nt * 128;
    const int kbase = kz * nkt * 64;

    __shared__ __align__(16) u16 As[128 * 64];
    __shared__ __align__(16) u16 Bs[128 * 64];

    const int tid = threadIdx.x;
    const u16* aptr[4]; const u16* bptr[4]; int adst[4];
#pragma unroll
    for (int it = 0; it < 4; it++) {
        int c = it * 256 + tid, r = c >> 3, q = c & 7;
        aptr[it] = A  + (size_t)r * ldA + kbase + q * 8;
        bptr[it] = BT + (size_t)(n0 + r) * ldBT + kbase + q * 8;
        adst[it] = r * 64 + ((q ^ (r & 7)) << 3);
    }

    const int lane = tid & 63, w = tid >> 6;
    const int wm = w >> 1, wn = w & 1;
    const int lr = lane & 15, lg = lane >> 4;
    int arow[4], brow[4];
#pragma unroll
    for (int i = 0; i < 4; i++) { arow[i] = wm * 64 + i * 16 + lr; brow[i] = wn * 64 + i * 16 + lr; }

    u16x8 pa[4], pb[4];
#pragma unroll
    for (int it = 0; it < 4; it++) {
        pa[it] = *(const u16x8*)(aptr[it]);
        pb[it] = *(const u16x8*)(bptr[it]);
    }

    f32x4 acc[4][4] = {};
    for (int kt = 0; kt < nkt; kt++) {
        __syncthreads();
#pragma unroll
        for (int it = 0; it < 4; it++) {
            *(u16x8*)&As[adst[it]] = pa[it];
            *(u16x8*)&Bs[adst[it]] = pb[it];
        }
        __syncthreads();
        if (kt + 1 < nkt) {
            int k = (kt + 1) * 64;
#pragma unroll
            for (int it = 0; it < 4; it++) {
                pa[it] = *(const u16x8*)(aptr[it] + k);
                pb[it] = *(const u16x8*)(bptr[it] + k);
            }
        }
#pragma unroll
        for (int ks = 0; ks < 2; ks++) {
            half8 aF[4], bF[4];
#pragma unroll
            for (int i = 0; i < 4; i++) {
                int ra = arow[i];
                aF[i] = *(const half8*)&As[ra * 64 + (((ks * 4 + lg) ^ (ra & 7)) << 3)];
            }
#pragma unroll
            for (int i = 0; i < 4; i++) {
                int rb = brow[i];
                bF[i] = *(const half8*)&Bs[rb * 64 + (((ks * 4 + lg) ^ (rb & 7)) << 3)];
            }
#pragma unroll
            for (int mi = 0; mi < 4; mi++)
#pragma unroll
                for (int ni = 0; ni < 4; ni++)
                    acc[mi][ni] = __builtin_amdgcn_mfma_f32_16x16x32_f16(aF[mi], bF[ni], acc[mi][ni], 0, 0, 0);
        }
    }

    float* Cb = C + (size_t)kz * 128 * ldC + n0;
#pragma unroll
    for (int mi = 0; mi < 4; mi++)
#pragma unroll
        for (int r = 0; r < 4; r++) {
            int grow = wm * 64 + mi * 16 + 4 * lg + r;
#pragma unroll
            for (int ni = 0; ni < 4; ni++)
                Cb[(size_t)grow * ldC + wn * 64 + ni * 16 + lr] = acc[mi][ni][r];
        }
}

// ---------------- softmax per batch row ----------------
__global__ __launch_bounds__(256) void softmax_kernel(const float* __restrict__ pooled,
                                                      float* __restrict__ attw,
                                                      u16* __restrict__ attwh) {
    __shared__ float rowm[N_];
    __shared__ float red[4];
    int b = blockIdx.x, tid = threadIdx.x;
    const float4* src = (const float4*)(pooled + (size_t)b * N_);
    float mx = -3.4e38f;
#pragma unroll
    for (int p = 0; p < 8; p++) {
        float4 v = src[tid + 256 * p];
        *((float4*)&rowm[(tid + 256 * p) * 4]) = v;
        mx = fmaxf(fmaxf(fmaxf(v.x, v.y), fmaxf(v.z, v.w)), mx);
    }
#pragma unroll
    for (int o = 32; o > 0; o >>= 1) mx = fmaxf(mx, __shfl_xor(mx, o));
    if ((tid & 63) == 0) red[tid >> 6] = mx;
    __syncthreads();
    mx = fmaxf(fmaxf(red[0], red[1]), fmaxf(red[2], red[3]));
    __syncthreads();
    float s = 0.f;
    for (int p = 0; p < 8; p++) {
        int i4 = tid + 256 * p;
        float4 v = *((float4*)&rowm[i4 * 4]);
        v.x = expf(v.x - mx); v.y = expf(v.y - mx);
        v.z = expf(v.z - mx); v.w = expf(v.w - mx);
        *((float4*)&rowm[i4 * 4]) = v;
        s += (v.x + v.y) + (v.z + v.w);
    }
#pragma unroll
    for (int o = 32; o > 0; o >>= 1) s += __shfl_xor(s, o);
    if ((tid & 63) == 0) red[tid >> 6] = s;
    __syncthreads();
    s = ((red[0] + red[1]) + (red[2] + red[3]));
    float inv = 1.0f / s;
    float4* dst = (float4*)(attw + (size_t)b * N_);
    u16* dh = attwh + (size_t)b * N_;
    for (int p = 0; p < 8; p++) {
        int i4 = tid + 256 * p;
        float4 v = *((float4*)&rowm[i4 * 4]);
        v.x *= inv; v.y *= inv; v.z *= inv; v.w *= inv;
        dst[i4] = v;
        ushort4 pk;
        pk.x = f2h(v.x); pk.y = f2h(v.y); pk.z = f2h(v.z); pk.w = f2h(v.w);
        *(ushort4*)(dh + (size_t)i4 * 4) = pk;
    }
}

// ---------------- att_ft reduce over K-splits ----------------
__global__ void attft_reduce_kernel(const float* __restrict__ p2, float* __restrict__ att_ft) {
    int i = blockIdx.x * 256 + threadIdx.x;    // 32768
    int b = i >> 9, d = i & 511;
    float s = 0.f;
#pragma unroll
    for (int kz = 0; kz < 8; kz++) s += p2[(size_t)kz * 128 * SD_ + (size_t)b * SD_ + d];
    att_ft[i] = s;
}

extern "C" void kernel_launch(void* const* d_in, const int* in_sizes, int n_in,
                              void* d_out, int out_size, void* d_ws, size_t ws_size,
                              hipStream_t stream) {
    (void)in_sizes; (void)n_in; (void)out_size; (void)ws_size;
    const float* ft  = (const float*)d_in[0];
    const float* sd  = (const float*)d_in[1];
    const int*   mask= (const int*)d_in[2];
    const float* g1  = (const float*)d_in[3];
    const float* bl1 = (const float*)d_in[4];
    const float* w1  = (const float*)d_in[5];
    const float* b1  = (const float*)d_in[6];
    const float* g2  = (const float*)d_in[7];
    const float* bl2 = (const float*)d_in[8];
    const float* w2  = (const float*)d_in[9];
    const float* b2  = (const float*)d_in[10];
    float* out = (float*)d_out;
    char* W = (char*)d_ws;

    u16*    w1T    = (u16*)(W + 0);          //  786432 B
    u16*    w2T    = (u16*)(W + 786432);     //  524288
    u16*    sdh    = (u16*)(W + 1310720);    // 8388608
    u16*    sdT    = (u16*)(W + 9699328);    // 8388608
    float*  b1p    = (float*)(W + 18087936); //    2048
    float*  b2p    = (float*)(W + 18089984); //    2048
    int*    list   = (int*)(W + 18092032);   //  147456
    int*    count  = (int*)(W + 18239488);   //     256
    float2* st1    = (float2*)(W + 18239744);//  294912
    float*  rstat  = (float*)(W + 18534656); // 2621440  [8][B][640][2]
    u16*    h      = (u16*)(W + 21156096);   // 41943040
    float*  partial= (float*)(W + 63099136); //  655360
    u16*    qsumh  = (u16*)(W + 63754496);   //  131072
    float*  pooled = (float*)(W + 63885568); // 4194304
    u16*    attwh  = (u16*)(W + 68079872);   // 2097152
    float*  p2     = (float*)(W + 70177024); // 2097152  -> total ~72.3 MB

    float* att_w  = out;
    float* att_ft = out + (size_t)B_ * N_;
    float* sd_out = out + (size_t)B_ * N_ + (size_t)B_ * SD_;

    zero_kernel<<<2048, 256, 0, stream>>>((unsigned int*)attwh, (unsigned int*)(qsumh + 64 * SD_), count);
    transpose_cvt_kernel<<<dim3(C_ / 64, SD_ / 64), 256, 0, stream>>>(w1, g1, w1T, C_, SD_);
    transpose_cvt_kernel<<<dim3(SD_ / 64, SD_ / 64), 256, 0, stream>>>(w2, g2, w2T, SD_, SD_);
    sd_prep_kernel<<<dim3(N_ / 64, SD_ / 64), 256, 0, stream>>>(sd, sdh, sdT);
    fold_bias_kernel<<<SD_, 64, 0, stream>>>(w1, b1, bl1, b1p, C_, SD_);
    fold_bias_kernel<<<SD_, 64, 0, stream>>>(w2, b2, bl2, b2p, SD_, SD_);
    compact_kernel<<<144, 256, 0, stream>>>(mask, list, count);
    ln1_stats_kernel<<<TOK_ / 4, 256, 0, stream>>>(ft, list, count, st1);
    gemm1_kernel<<<dim3(B_ * MT_, 4), 256, 0, stream>>>(ft, w1T, b1p, list, count, st1, h, rstat);
    gemm2_kernel<<<dim3(B_ * MT_, 4), 256, 0, stream>>>(h, w2T, count, rstat, partial);
    qsum_reduce_kernel<<<128, 256, 0, stream>>>(partial, count, b2p, qsumh);
    gemm_plain_kernel<<<dim3(1, 64), 256, 0, stream>>>(qsumh, SD_, sdh, SD_, pooled, N_, 8);
    softmax_kernel<<<B_, 256, 0, stream>>>(pooled, att_w, attwh);
    gemm_plain_kernel<<<dim3(8, 4), 256, 0, stream>>>(attwh, N_, sdT, N_, p2, SD_, 16);
    attft_reduce_kernel<<<128, 256, 0, stream>>>(p2, att_ft);
    hipMemcpyAsync(sd_out, sd, (size_t)N_ * SD_ * sizeof(float), hipMemcpyDeviceToDevice, stream);
}